// Round 8
// baseline (1025.725 us; speedup 1.0000x reference)
//
#include <hip/hip_runtime.h>
#include <hip/hip_bf16.h>
#include <hip/hip_fp16.h>

typedef _Float16 f16;
typedef __attribute__((ext_vector_type(8))) _Float16 f16x8;
typedef __attribute__((ext_vector_type(4))) _Float16 f16x4;
typedef __attribute__((ext_vector_type(2))) _Float16 f16x2;
typedef __attribute__((ext_vector_type(4))) float f32x4;

#define AS1(p) ((const __attribute__((address_space(1))) void*)(p))
#define AS3(p) ((__attribute__((address_space(3))) void*)(p))

// ---------------- weight fp32 -> f16 conversion (qkv + proj only) ----------------
__global__ __launch_bounds__(256) void cvt_weights(
    const float* __restrict__ wq, const float* __restrict__ wp,
    f16* __restrict__ o) {
  int i = blockIdx.x * 256 + threadIdx.x;  // grid sized exactly 262144
  float v = (i < 196608) ? wq[i] : wp[i - 196608];
  o[i] = (f16)v;
}

// ---------------- FFN weights -> MFMA fragment-lane packed order ----------------
// W1p flat[t*8+e], t = n16*512 + kk*64 + lane: value = w1[n16*16+l16][kk*32+qd*8+e]
// W2p flat[u*8+e], u = n16*2048 + kk*64 + lane: value = w2[n16*16+l16][kk*32+qd*8+e]
// (lane = qd*16+l16). A wave's B-fragment load becomes 64 lanes x 16B CONTIGUOUS.
__global__ __launch_bounds__(256) void prep_wfrag(
    const float* __restrict__ wf1, const float* __restrict__ wf2,
    f16* __restrict__ W1p, f16* __restrict__ W2p) {
  const int t = blockIdx.x * 256 + threadIdx.x;   // grid = 256 -> 65536
  if (t < 32768) {
    const int n16 = t >> 9, kk = (t >> 6) & 7, lane = t & 63;
    const int qd = lane >> 4, l16 = lane & 15;
    const float* src = wf1 + (n16 * 16 + l16) * 256 + kk * 32 + qd * 8;
    f16x8 o;
    #pragma unroll
    for (int e = 0; e < 8; ++e) o[e] = (f16)src[e];
    *(f16x8*)(W1p + (long)t * 8) = o;
  } else {
    const int u = t - 32768;
    const int n16 = u >> 11, kk = (u >> 6) & 31, lane = u & 63;
    const int qd = lane >> 4, l16 = lane & 15;
    const float* src = wf2 + (n16 * 16 + l16) * 1024 + kk * 32 + qd * 8;
    f16x8 o;
    #pragma unroll
    for (int e = 0; e < 8; ++e) o[e] = (f16)src[e];
    *(f16x8*)(W2p + (long)u * 8) = o;
  }
}

// ---------------- bias table -> MFMA fragment-lane order, pre-scaled by log2e ----
__global__ __launch_bounds__(256) void prep_bias(
    const float* __restrict__ bt, float* __restrict__ T) {
  const int flat = blockIdx.x * 256 + threadIdx.x;   // grid = 128 -> 32768
  const int h = flat >> 12, l = (flat >> 6) & 63, s = flat & 63;
  const int i = s >> 4, j = (s >> 2) & 3, r = s & 3;
  const int n = 16 * i + 4 * (l >> 4) + r;
  const int m = 16 * j + (l & 15);
  const int idx = ((n >> 3) - (m >> 3) + 7) * 15 + ((n & 7) - (m & 7) + 7);
  T[flat] = bt[idx * 8 + h] * 1.4426950408889634f;
}

// ---------------- LayerNorm (one wave per 256-elem row) ----------------
template<bool PART, typename TIN>
__global__ __launch_bounds__(256) void ln_rows(
    const TIN* __restrict__ x, const float* __restrict__ g,
    const float* __restrict__ b, f16* __restrict__ out) {
  const int t = blockIdx.x * 4 + (threadIdx.x >> 6);   // token row within chunk
  const int lane = threadIdx.x & 63;
  float v0, v1, v2, v3;
  if constexpr (sizeof(TIN) == 4) {
    const float4 v = ((const float4*)(x + (long)t * 256))[lane];
    v0 = v.x; v1 = v.y; v2 = v.z; v3 = v.w;
  } else {
    const f16x4 v = ((const f16x4*)(x + (long)t * 256))[lane];
    v0 = (float)v[0]; v1 = (float)v[1]; v2 = (float)v[2]; v3 = (float)v[3];
  }
  float s  = v0 + v1 + v2 + v3;
  float ss = v0*v0 + v1*v1 + v2*v2 + v3*v3;
  #pragma unroll
  for (int off = 32; off; off >>= 1) {
    s  += __shfl_xor(s, off);
    ss += __shfl_xor(ss, off);
  }
  const float mu = s * (1.0f / 256.0f);
  const float var = ss * (1.0f / 256.0f) - mu * mu;
  const float rs = rsqrtf(var + 1e-5f);
  const float4 gv = ((const float4*)g)[lane];
  const float4 bv = ((const float4*)b)[lane];
  long row;
  if (PART) {
    const int bI = t >> 12, l = t & 4095;
    const int hh = l >> 6, w2 = l & 63;
    const int wi = bI * 64 + (hh >> 3) * 8 + (w2 >> 3);
    const int n  = (hh & 7) * 8 + (w2 & 7);
    row = (long)wi * 64 + n;
  } else {
    row = t;
  }
  f16x4 o4;
  o4[0] = (f16)((v0 - mu) * rs * gv.x + bv.x);
  o4[1] = (f16)((v1 - mu) * rs * gv.y + bv.y);
  o4[2] = (f16)((v2 - mu) * rs * gv.z + bv.z);
  o4[3] = (f16)((v3 - mu) * rs * gv.w + bv.w);
  *(f16x4*)(out + row * 256 + lane * 4) = o4;
}

// ---------------- GEMM: C[M,N] = A[M,K] @ Bw[N,K]^T + bias (qkv / proj) ------
// EPI 0: f16 out = v                               (qkv)
// EPI 1: f16 out[window-reversed row] = x + v      (proj -> x1 f16), resid fp32
// BK=64 double-buffered counted-vmcnt pipeline (round-6 structure).
// Epilogue: slices are WAVE-PRIVATE (2KB per wid) and LDS ops are in-order
// within a wave -> no __syncthreads needed anywhere in the epilogue.
template<int EPI, int K>
__global__ __launch_bounds__(256) void gemm_bt(
    const f16* __restrict__ A, const f16* __restrict__ Bw,
    const float* __restrict__ bias, const float* __restrict__ residf,
    const f16* __restrict__ residh,
    f16* __restrict__ outh, float* __restrict__ outf, int N) {
  __shared__ f16 As[2][128 * 64];
  __shared__ f16 Bs[2][128 * 64];
  const int tid  = threadIdx.x;
  const int wid  = tid >> 6;
  const int lane = tid & 63;
  const int qd   = lane >> 4;       // quad 0..3
  const int l16  = lane & 15;
  const int gx  = gridDim.x;
  const int nwg = gx * gridDim.y;
  const int g   = blockIdx.y * gx + blockIdx.x;
  const int gs  = (g & 7) * (nwg >> 3) + (g >> 3);
  const long tM = (long)(gs / gx) * 128;
  const int  tN = (gs % gx) * 128;
  const int sgrow = lane >> 3;                       // row within 8-row group
  const int scol  = ((lane & 7) ^ sgrow) * 8;        // pre-swizzled global col
  const int wm = (wid >> 1) * 64;
  const int wn = (wid & 1) * 64;

  f32x4 acc[4][4];
  #pragma unroll
  for (int i = 0; i < 4; ++i)
    #pragma unroll
    for (int j = 0; j < 4; ++j) acc[i][j] = (f32x4){0.f, 0.f, 0.f, 0.f};

  const int nt = K / 64;
  f16x8 af[2][4], bf[2][4];

  auto stage_tile = [&](int tt) {
    const int k0 = tt * 64;
    f16* Ad = &As[tt & 1][0];
    f16* Bd = &Bs[tt & 1][0];
    #pragma unroll
    for (int u = 0; u < 4; ++u) {
      const int gidx = wid * 4 + u;                  // group 0..15
      const int row  = gidx * 8 + sgrow;             // 0..127
      __builtin_amdgcn_global_load_lds(AS1(A + (tM + row) * K + k0 + scol),
                                       AS3(&Ad[gidx * 512]), 16, 0, 0);
      __builtin_amdgcn_global_load_lds(AS1(Bw + (long)(tN + row) * K + k0 + scol),
                                       AS3(&Bd[gidx * 512]), 16, 0, 0);
    }
  };
  auto load_frags = [&](int cb) {
    #pragma unroll
    for (int kk = 0; kk < 2; ++kk) {
      #pragma unroll
      for (int i = 0; i < 4; ++i) {
        const int row = wm + i * 16 + l16;
        af[kk][i] = *(const f16x8*)&As[cb][row * 64 + (((kk << 2) | qd) ^ (row & 7)) * 8];
      }
      #pragma unroll
      for (int j = 0; j < 4; ++j) {
        const int row = wn + j * 16 + l16;
        bf[kk][j] = *(const f16x8*)&Bs[cb][row * 64 + (((kk << 2) | qd) ^ (row & 7)) * 8];
      }
    }
  };
  auto do_mfma = [&]() {
    #pragma unroll
    for (int kk = 0; kk < 2; ++kk)
      #pragma unroll
      for (int i = 0; i < 4; ++i)
        #pragma unroll
        for (int j = 0; j < 4; ++j)
          acc[i][j] = __builtin_amdgcn_mfma_f32_16x16x32_f16(af[kk][i], bf[kk][j], acc[i][j], 0, 0, 0);
  };

  stage_tile(0);
  stage_tile(1);

  for (int t = 0; t < nt - 2; ++t) {
    asm volatile("s_waitcnt vmcnt(8)" ::: "memory");
    __builtin_amdgcn_s_barrier();
    load_frags(t & 1);
    asm volatile("s_waitcnt lgkmcnt(0)" ::: "memory");
    __builtin_amdgcn_s_barrier();
    stage_tile(t + 2);
    do_mfma();
  }
  asm volatile("s_waitcnt vmcnt(8)" ::: "memory");
  __builtin_amdgcn_s_barrier();
  load_frags(nt & 1);
  do_mfma();
  asm volatile("s_waitcnt vmcnt(0)" ::: "memory");
  __builtin_amdgcn_s_barrier();
  load_frags((nt - 1) & 1);   // buf 1; epilogue slices live in As[0] -> no alias
  do_mfma();

  float bb[4];
  #pragma unroll
  for (int j = 0; j < 4; ++j) bb[j] = bias[tN + wn + j * 16 + l16];

  if (EPI == 3) {
    #pragma unroll
    for (int j = 0; j < 4; ++j) {
      const int col = tN + wn + j * 16 + l16;
      #pragma unroll
      for (int i = 0; i < 4; ++i) {
        #pragma unroll
        for (int r = 0; r < 4; ++r) {
          const long row = tM + wm + i * 16 + qd * 4 + r;
          const long off = row * 256 + col;
          outf[off] = (float)residh[off] + acc[i][j][r] + bb[j];
        }
      }
    }
  } else {
    // Wave-private LDS-staged f16 epilogue, barrier-free.
    f16* slice = &As[0][0] + wid * 1024;  // per-wave 16x64 tile (2 KB)
    const int rrow = lane >> 3;          // 0..7
    const int seg  = lane & 7;           // 0..7
    #pragma unroll
    for (int i = 0; i < 4; ++i) {
      #pragma unroll
      for (int j = 0; j < 4; ++j) {
        #pragma unroll
        for (int r = 0; r < 4; ++r) {
          float v = acc[i][j][r] + bb[j];
          if (EPI == 2) {
            const float u2 = v * v;
            const float w  = v * (-2.3022082f - 0.10294324f * u2);
            const float e  = __builtin_amdgcn_exp2f(w);
            v = v * __builtin_amdgcn_rcpf(1.0f + e);
          }
          const int r16 = qd * 4 + r;
          slice[r16 * 64 + ((j * 16 + l16) ^ ((r16 & 7) << 3))] = (f16)v;
        }
      }
      #pragma unroll
      for (int hrow = 0; hrow < 16; hrow += 8) {
        const int lrow = hrow + rrow;                       // 0..15
        const f16x8 v8 = *(const f16x8*)(slice + lrow * 64 + (seg ^ (lrow & 7)) * 8);
        const long grow = tM + wm + i * 16 + lrow;
        const int  gc   = tN + wn + seg * 8;
        if (EPI == 1) {
          const int rw = (int)grow;
          const int wi = rw >> 6, n = rw & 63;
          const int bI = wi >> 6, wloc = wi & 63;
          const int hh = (wloc >> 3) * 8 + (n >> 3);
          const int w2 = (wloc & 7) * 8 + (n & 7);
          const long prow = (long)bI * 4096 + hh * 64 + w2;
          const float* rp = residf + prow * 256 + gc;
          f16x8 o;
          #pragma unroll
          for (int k = 0; k < 8; ++k) o[k] = (f16)(rp[k] + (float)v8[k]);
          *(f16x8*)(outh + prow * 256 + gc) = o;
        } else {
          *(f16x8*)(outh + grow * N + gc) = v8;
        }
      }
    }
  }
}

// ---------------- fused FFN: out = x1 + gelu(xn2@w1^T+b1) @ w2^T + b2 --------
// Identical structure to round-7 v1 EXCEPT weights come from the fragment-
// packed W1p/W2p: each wave's B-frag load is 64 lanes x 16B CONTIGUOUS (1KB,
// one L2 request) instead of 16 scattered 64B lines. That was v1's stall.
__global__ __launch_bounds__(512, 2) void ffn_fused(
    const f16* __restrict__ A, const f16* __restrict__ W1p, const f16* __restrict__ W2p,
    const float* __restrict__ b1f, const float* __restrict__ b2f,
    const f16* __restrict__ residh, float* __restrict__ outf) {
  __shared__ f16 As[128 * 256];
  __shared__ f16 Hs[128 * 256];
  const int tid = threadIdx.x;
  const int wid = tid >> 6, lane = tid & 63;
  const int qd = lane >> 4, l16 = lane & 15;
  const int wm = (wid >> 2) * 64, wn = (wid & 3) * 64;
  const int wn4 = (wid & 3) * 4;          // wn>>4
  const int nwg = gridDim.x;
  const int g = blockIdx.x;
  const int gs = (g & 7) * (nwg >> 3) + (g >> 3);
  const long tM = (long)gs * 128;

  // ---- stage A once: 128 rows x 512B ----
  #pragma unroll
  for (int u = 0; u < 8; ++u) {
    const int row = u * 16 + (tid >> 5);
    const int c = tid & 31;
    const int cs = (c & ~7) | ((c & 7) ^ (row & 7));   // involution pre-swizzle
    __builtin_amdgcn_global_load_lds(AS1(A + (tM + row) * 256 + cs * 8),
                                     AS3(&As[row * 256 + c * 8]), 16, 0, 0);
  }
  asm volatile("s_waitcnt vmcnt(0)" ::: "memory");
  __builtin_amdgcn_s_barrier();

  f32x4 acc2[4][4];
  #pragma unroll
  for (int i = 0; i < 4; ++i)
    #pragma unroll
    for (int j = 0; j < 4; ++j) acc2[i][j] = (f32x4){0.f, 0.f, 0.f, 0.f};

  for (int hc = 0; hc < 4; ++hc) {
    // ---- fc1 chunk: acch = A @ w1[hc*256+wn.., :]^T  (K=256) ----
    f32x4 acch[4][4];
    #pragma unroll
    for (int i = 0; i < 4; ++i)
      #pragma unroll
      for (int j = 0; j < 4; ++j) acch[i][j] = (f32x4){0.f, 0.f, 0.f, 0.f};
    #pragma unroll
    for (int kk = 0; kk < 8; ++kk) {
      f16x8 a4[4], b4[4];
      #pragma unroll
      for (int i = 0; i < 4; ++i) {
        const int row = wm + i * 16 + l16;
        const int cg = kk * 4 + qd;
        const int cs = (cg & ~7) | ((cg & 7) ^ (row & 7));
        a4[i] = *(const f16x8*)&As[row * 256 + cs * 8];
      }
      #pragma unroll
      for (int j = 0; j < 4; ++j)
        b4[j] = *(const f16x8*)(W1p + ((long)(((hc * 16 + wn4 + j) * 8 + kk) * 64 + lane) << 3));
      #pragma unroll
      for (int i = 0; i < 4; ++i)
        #pragma unroll
        for (int j = 0; j < 4; ++j)
          acch[i][j] = __builtin_amdgcn_mfma_f32_16x16x32_f16(a4[i], b4[j], acch[i][j], 0, 0, 0);
    }
    __syncthreads();   // previous hc's fc2 reads of Hs complete
    // ---- gelu + bias -> Hs (swizzled) ----
    #pragma unroll
    for (int j = 0; j < 4; ++j) {
      const float bb1 = b1f[hc * 256 + wn + j * 16 + l16];
      #pragma unroll
      for (int i = 0; i < 4; ++i) {
        #pragma unroll
        for (int r = 0; r < 4; ++r) {
          float v = acch[i][j][r] + bb1;
          const float u2 = v * v;
          const float w  = v * (-2.3022082f - 0.10294324f * u2);
          const float e  = __builtin_amdgcn_exp2f(w);
          v = v * __builtin_amdgcn_rcpf(1.0f + e);
          const int r16 = qd * 4 + r;
          const int row = wm + i * 16 + r16;
          Hs[row * 256 + wn + ((j * 16 + l16) ^ ((r16 & 7) << 3))] = (f16)v;
        }
      }
    }
    __syncthreads();   // Hs visible to all waves
    // ---- fc2 chunk: acc2 += Hs @ w2[wn.., hc*256..]^T ----
    #pragma unroll
    for (int kk = 0; kk < 8; ++kk) {
      f16x8 ah[4], bh[4];
      #pragma unroll
      for (int i = 0; i < 4; ++i) {
        const int row = wm + i * 16 + l16;
        const int cg = kk * 4 + qd;
        const int cs = (cg & ~7) | ((cg & 7) ^ (row & 7));
        ah[i] = *(const f16x8*)&Hs[row * 256 + cs * 8];
      }
      #pragma unroll
      for (int j = 0; j < 4; ++j)
        bh[j] = *(const f16x8*)(W2p + ((long)(((wn4 + j) * 32 + hc * 8 + kk) * 64 + lane) << 3));
      #pragma unroll
      for (int i = 0; i < 4; ++i)
        #pragma unroll
        for (int j = 0; j < 4; ++j)
          acc2[i][j] = __builtin_amdgcn_mfma_f32_16x16x32_f16(ah[i], bh[j], acc2[i][j], 0, 0, 0);
    }
  }

  // ---- epilogue: out fp32 = x1h + acc2 + b2 ----
  #pragma unroll
  for (int j = 0; j < 4; ++j) {
    const int col = wn + j * 16 + l16;
    const float bb2 = b2f[col];
    #pragma unroll
    for (int i = 0; i < 4; ++i) {
      #pragma unroll
      for (int r = 0; r < 4; ++r) {
        const long row = tM + wm + i * 16 + qd * 4 + r;
        const long off = row * 256 + col;
        outf[off] = (float)residh[off] + acc2[i][j][r] + bb2;
      }
    }
  }
}

// ---------------- windowed attention: MFMA flash, one wave per (window, head) ----------------
__global__ __launch_bounds__(256, 3) void attn_win(
    const f16* __restrict__ qkv, const float* __restrict__ bt,  // bt = T[8][64][64] pre-scaled
    f16* __restrict__ out) {
  __shared__ __align__(16) char SMEM[4 * 12800];
  const int wid = threadIdx.x >> 6, lane = threadIdx.x & 63;
  const int qd = lane >> 4, l16 = lane & 15;
  const int unit = blockIdx.x * 4 + wid;   // (window,head) unit within chunk
  const int wi = unit >> 3, h = unit & 7;
  char* W = SMEM + wid * 12800;
  f16* VT = (f16*)W;               // stride 72 f16 per d-row
  char* Pb = W + 4608;

  const f16* qbase = qkv + (long)wi * 64 * 768 + h * 32;

  f16x8 qa[4], kb[4];
  #pragma unroll
  for (int i = 0; i < 4; ++i)
    qa[i] = *(const f16x8*)(qbase + (16 * i + l16) * 768 + qd * 8);
  #pragma unroll
  for (int j = 0; j < 4; ++j)
    kb[j] = *(const f16x8*)(qbase + 256 + (16 * j + l16) * 768 + qd * 8);

  #pragma unroll
  for (int it = 0; it < 4; ++it) {
    const f16x8 v8 = *(const f16x8*)(qbase + 512 + (16 * it + l16) * 768 + qd * 8);
    #pragma unroll
    for (int e = 0; e < 8; ++e)
      VT[(qd * 8 + e) * 72 + 16 * it + l16] = v8[e];
  }

  f32x4 S[4][4];
  #pragma unroll
  for (int i = 0; i < 4; ++i)
    #pragma unroll
    for (int j = 0; j < 4; ++j) S[i][j] = (f32x4){0.f, 0.f, 0.f, 0.f};
  #pragma unroll
  for (int i = 0; i < 4; ++i)
    #pragma unroll
    for (int j = 0; j < 4; ++j)
      S[i][j] = __builtin_amdgcn_mfma_f32_16x16x32_f16(qa[i], kb[j], S[i][j], 0, 0, 0);

  const float SC = 0.17677669529663687f * 1.4426950408889634f;  // 1/sqrt(32)*log2e
  const float* Tb = bt + ((h * 64 + lane) << 6);
  #pragma unroll
  for (int i = 0; i < 4; ++i) {
    f32x4 b0 = *(const f32x4*)(Tb + i * 16);
    f32x4 b1 = *(const f32x4*)(Tb + i * 16 + 4);
    f32x4 b2 = *(const f32x4*)(Tb + i * 16 + 8);
    f32x4 b3 = *(const f32x4*)(Tb + i * 16 + 12);
    #pragma unroll
    for (int r = 0; r < 4; ++r) {
      S[i][0][r] = S[i][0][r] * SC + b0[r];
      S[i][1][r] = S[i][1][r] * SC + b1[r];
      S[i][2][r] = S[i][2][r] * SC + b2[r];
      S[i][3][r] = S[i][3][r] * SC + b3[r];
    }
  }

  float inv[4][4];
  #pragma unroll
  for (int i = 0; i < 4; ++i) {
    #pragma unroll
    for (int r = 0; r < 4; ++r) {
      float mx = fmaxf(fmaxf(S[i][0][r], S[i][1][r]), fmaxf(S[i][2][r], S[i][3][r]));
      #pragma unroll
      for (int msk = 1; msk < 16; msk <<= 1) mx = fmaxf(mx, __shfl_xor(mx, msk));
      float s0 = 0.f;
      #pragma unroll
      for (int j = 0; j < 4; ++j) {
        const float p = __builtin_amdgcn_exp2f(S[i][j][r] - mx);
        S[i][j][r] = p;
        s0 += p;
      }
      #pragma unroll
      for (int msk = 1; msk < 16; msk <<= 1) s0 += __shfl_xor(s0, msk);
      inv[i][r] = __builtin_amdgcn_rcpf(s0);
    }
  }

  #pragma unroll
  for (int i = 0; i < 4; ++i) {
    #pragma unroll
    for (int r = 0; r < 4; ++r) {
      const int n = 16 * i + 4 * qd + r;
      char* rowp = Pb + n * 128;
      const int sw = (n & 7) << 4;
      #pragma unroll
      for (int j = 0; j < 4; ++j)
        *(f16*)(rowp + ((j * 32 + l16 * 2) ^ sw)) = (f16)S[i][j][r];
    }
  }

  f32x4 O[4][2];
  #pragma unroll
  for (int i = 0; i < 4; ++i) {
    O[i][0] = (f32x4){0.f, 0.f, 0.f, 0.f};
    O[i][1] = (f32x4){0.f, 0.f, 0.f, 0.f};
  }
  #pragma unroll
  for (int kk = 0; kk < 2; ++kk) {
    f16x8 vb[2];
    #pragma unroll
    for (int jj = 0; jj < 2; ++jj)
      vb[jj] = *(const f16x8*)((const char*)W + (16 * jj + l16) * 144 + kk * 64 + qd * 16);
    #pragma unroll
    for (int i = 0; i < 4; ++i) {
      const f16x8 pa = *(const f16x8*)(Pb + (16 * i + l16) * 128 +
                                       ((kk * 64 + qd * 16) ^ ((l16 & 7) << 4)));
      #pragma unroll
      for (int jj = 0; jj < 2; ++jj)
        O[i][jj] = __builtin_amdgcn_mfma_f32_16x16x32_f16(pa, vb[jj], O[i][jj], 0, 0, 0);
    }
  }

  #pragma unroll
  for (int i = 0; i < 4; ++i) {
    #pragma unroll
    for (int jj = 0; jj < 2; ++jj) {
      #pragma unroll
      for (int r = 0; r < 4; ++r) {
        const int n = 16 * i + 4 * qd + r;
        *(f16*)(Pb + n * 80 + jj * 32 + l16 * 2) = (f16)(O[i][jj][r] * inv[i][r]);
      }
    }
  }
  #pragma unroll
  for (int it = 0; it < 4; ++it) {
    const int row = 16 * it + l16;
    const f16x8 o8 = *(const f16x8*)(Pb + row * 80 + qd * 16);
    *(f16x8*)(out + ((long)wi * 64 + row) * 256 + h * 32 + qd * 8) = o8;
  }
}

// ---------------- launch ----------------
extern "C" void kernel_launch(void* const* d_in, const int* in_sizes, int n_in,
                              void* d_out, int out_size, void* d_ws, size_t ws_size,
                              hipStream_t stream) {
  const float* x     = (const float*)d_in[0];
  const float* g1    = (const float*)d_in[2];
  const float* b1    = (const float*)d_in[3];
  const float* wqkv  = (const float*)d_in[4];
  const float* bqkv  = (const float*)d_in[5];
  const float* btab  = (const float*)d_in[6];
  const float* wproj = (const float*)d_in[7];
  const float* bproj = (const float*)d_in[8];
  const float* g2    = (const float*)d_in[9];
  const float* b2    = (const float*)d_in[10];
  const float* wfc1  = (const float*)d_in[11];
  const float* bfc1  = (const float*)d_in[12];
  const float* wfc2  = (const float*)d_in[13];
  const float* bfc2  = (const float*)d_in[14];
  float* out = (float*)d_out;

  char* ws = (char*)d_ws;
  // head region [0, 2MB): wq16+wp16 512KB | Tbuf 128KB | W1p 512KB | W2p 512KB
  f16* wq16 = (f16*)ws;                       // 196608 f16
  f16* wp16 = wq16 + 196608;                  // 65536 f16, ends at 512KB
  float* Tbuf = (float*)(ws + 524288);        // 128KB
  f16* W1p = (f16*)(ws + 655360);             // 512KB
  f16* W2p = (f16*)(ws + 1179648);            // 512KB, ends at ~1.66MB

  // Per-image f16 buffers: xn 2MB | qkv 6MB | x1 2MB | xn2 2MB
  int CH = 1;
  for (int cand = 32; cand >= 1; cand >>= 1) {
    const size_t need = 2097152ULL + (size_t)cand * 12582912ULL;
    if (need <= ws_size) { CH = cand; break; }
  }
  const int NC = 32 / CH;

  const size_t O_xn  = 2097152ULL;
  const size_t O_qkv = O_xn  + (size_t)CH * 2097152ULL;
  const size_t O_x1  = O_qkv + (size_t)CH * 6291456ULL;
  const size_t O_xn2 = O_x1  + (size_t)CH * 2097152ULL;
  f16* xnw  = (f16*)(ws + O_xn);    // ln1 out / attn out
  f16* qkvb = (f16*)(ws + O_qkv);
  f16* x1h  = (f16*)(ws + O_x1);
  f16* xn2  = (f16*)(ws + O_xn2);

  cvt_weights<<<1024, 256, 0, stream>>>(wqkv, wproj, wq16);
  prep_bias<<<128, 256, 0, stream>>>(btab, Tbuf);
  prep_wfrag<<<256, 256, 0, stream>>>(wfc1, wfc2, W1p, W2p);

  const long imgElems = 4096L * 256;   // fp32 elems per image
  for (int c = 0; c < NC; ++c) {
    const float* xc  = x   + (long)c * CH * imgElems;
    float*       oc  = out + (long)c * CH * imgElems;
    ln_rows<true, float><<<CH * 1024, 256, 0, stream>>>(xc, g1, b1, xnw);
    gemm_bt<0, 256><<<dim3(6, CH * 32), 256, 0, stream>>>(xnw, wq16, bqkv, nullptr, nullptr, qkvb, nullptr, 768);
    attn_win<<<CH * 128, 256, 0, stream>>>(qkvb, Tbuf, xnw);
    gemm_bt<1, 256><<<dim3(2, CH * 32), 256, 0, stream>>>(xnw, wp16, bproj, xc, nullptr, x1h, nullptr, 256);
    ln_rows<false, f16><<<CH * 1024, 256, 0, stream>>>(x1h, g2, b2, xn2);
    ffn_fused<<<CH * 32, 512, 0, stream>>>(xn2, W1p, W2p, bfc1, bfc2, x1h, oc);
  }
}

// Round 9
// 681.263 us; speedup vs baseline: 1.5056x; 1.5056x over previous
//
#include <hip/hip_runtime.h>
#include <hip/hip_bf16.h>
#include <hip/hip_fp16.h>

typedef _Float16 f16;
typedef __attribute__((ext_vector_type(8))) _Float16 f16x8;
typedef __attribute__((ext_vector_type(4))) _Float16 f16x4;
typedef __attribute__((ext_vector_type(2))) _Float16 f16x2;
typedef __attribute__((ext_vector_type(4))) float f32x4;

#define AS1(p) ((const __attribute__((address_space(1))) void*)(p))
#define AS3(p) ((__attribute__((address_space(3))) void*)(p))

// ---------------- weight fp32 -> f16 conversion (qkv + proj only) ----------------
__global__ __launch_bounds__(256) void cvt_weights(
    const float* __restrict__ wq, const float* __restrict__ wp,
    f16* __restrict__ o) {
  int i = blockIdx.x * 256 + threadIdx.x;  // grid sized exactly 262144
  float v = (i < 196608) ? wq[i] : wp[i - 196608];
  o[i] = (f16)v;
}

// ---------------- FFN weights -> MFMA fragment-lane packed order ----------------
// W1p flat[t*8+e], t = n16*512 + kk*64 + lane: value = w1[n16*16+l16][kk*32+qd*8+e]
// W2p flat[u*8+e], u = n16*2048 + kk*64 + lane: value = w2[n16*16+l16][kk*32+qd*8+e]
// (lane = qd*16+l16). A wave's B-fragment load = 64 lanes x 16B CONTIGUOUS (1KB).
__global__ __launch_bounds__(256) void prep_wfrag(
    const float* __restrict__ wf1, const float* __restrict__ wf2,
    f16* __restrict__ W1p, f16* __restrict__ W2p) {
  const int t = blockIdx.x * 256 + threadIdx.x;   // grid = 256 -> 65536
  if (t < 32768) {
    const int n16 = t >> 9, kk = (t >> 6) & 7, lane = t & 63;
    const int qd = lane >> 4, l16 = lane & 15;
    const float* src = wf1 + (n16 * 16 + l16) * 256 + kk * 32 + qd * 8;
    f16x8 o;
    #pragma unroll
    for (int e = 0; e < 8; ++e) o[e] = (f16)src[e];
    *(f16x8*)(W1p + (long)t * 8) = o;
  } else {
    const int u = t - 32768;
    const int n16 = u >> 11, kk = (u >> 6) & 31, lane = u & 63;
    const int qd = lane >> 4, l16 = lane & 15;
    const float* src = wf2 + (n16 * 16 + l16) * 1024 + kk * 32 + qd * 8;
    f16x8 o;
    #pragma unroll
    for (int e = 0; e < 8; ++e) o[e] = (f16)src[e];
    *(f16x8*)(W2p + (long)u * 8) = o;
  }
}

// ---------------- bias table -> MFMA fragment-lane order, pre-scaled by log2e ----
__global__ __launch_bounds__(256) void prep_bias(
    const float* __restrict__ bt, float* __restrict__ T) {
  const int flat = blockIdx.x * 256 + threadIdx.x;   // grid = 128 -> 32768
  const int h = flat >> 12, l = (flat >> 6) & 63, s = flat & 63;
  const int i = s >> 4, j = (s >> 2) & 3, r = s & 3;
  const int n = 16 * i + 4 * (l >> 4) + r;
  const int m = 16 * j + (l & 15);
  const int idx = ((n >> 3) - (m >> 3) + 7) * 15 + ((n & 7) - (m & 7) + 7);
  T[flat] = bt[idx * 8 + h] * 1.4426950408889634f;
}

// ---------------- LayerNorm (one wave per 256-elem row) ----------------
template<bool PART, typename TIN>
__global__ __launch_bounds__(256) void ln_rows(
    const TIN* __restrict__ x, const float* __restrict__ g,
    const float* __restrict__ b, f16* __restrict__ out) {
  const int t = blockIdx.x * 4 + (threadIdx.x >> 6);   // token row within chunk
  const int lane = threadIdx.x & 63;
  float v0, v1, v2, v3;
  if constexpr (sizeof(TIN) == 4) {
    const float4 v = ((const float4*)(x + (long)t * 256))[lane];
    v0 = v.x; v1 = v.y; v2 = v.z; v3 = v.w;
  } else {
    const f16x4 v = ((const f16x4*)(x + (long)t * 256))[lane];
    v0 = (float)v[0]; v1 = (float)v[1]; v2 = (float)v[2]; v3 = (float)v[3];
  }
  float s  = v0 + v1 + v2 + v3;
  float ss = v0*v0 + v1*v1 + v2*v2 + v3*v3;
  #pragma unroll
  for (int off = 32; off; off >>= 1) {
    s  += __shfl_xor(s, off);
    ss += __shfl_xor(ss, off);
  }
  const float mu = s * (1.0f / 256.0f);
  const float var = ss * (1.0f / 256.0f) - mu * mu;
  const float rs = rsqrtf(var + 1e-5f);
  const float4 gv = ((const float4*)g)[lane];
  const float4 bv = ((const float4*)b)[lane];
  long row;
  if (PART) {
    const int bI = t >> 12, l = t & 4095;
    const int hh = l >> 6, w2 = l & 63;
    const int wi = bI * 64 + (hh >> 3) * 8 + (w2 >> 3);
    const int n  = (hh & 7) * 8 + (w2 & 7);
    row = (long)wi * 64 + n;
  } else {
    row = t;
  }
  f16x4 o4;
  o4[0] = (f16)((v0 - mu) * rs * gv.x + bv.x);
  o4[1] = (f16)((v1 - mu) * rs * gv.y + bv.y);
  o4[2] = (f16)((v2 - mu) * rs * gv.z + bv.z);
  o4[3] = (f16)((v3 - mu) * rs * gv.w + bv.w);
  *(f16x4*)(out + row * 256 + lane * 4) = o4;
}

// ---------------- GEMM: C[M,N] = A[M,K] @ Bw[N,K]^T + bias (qkv / proj) ------
// EPI 0: f16 out = v                               (qkv)
// EPI 1: f16 out[window-reversed row] = x + v      (proj -> x1 f16), resid fp32
// BK=64 double-buffered counted-vmcnt pipeline; barrier-free wave-private
// f16 epilogue.
template<int EPI, int K>
__global__ __launch_bounds__(256) void gemm_bt(
    const f16* __restrict__ A, const f16* __restrict__ Bw,
    const float* __restrict__ bias, const float* __restrict__ residf,
    const f16* __restrict__ residh,
    f16* __restrict__ outh, float* __restrict__ outf, int N) {
  __shared__ f16 As[2][128 * 64];
  __shared__ f16 Bs[2][128 * 64];
  const int tid  = threadIdx.x;
  const int wid  = tid >> 6;
  const int lane = tid & 63;
  const int qd   = lane >> 4;       // quad 0..3
  const int l16  = lane & 15;
  const int gx  = gridDim.x;
  const int nwg = gx * gridDim.y;
  const int g   = blockIdx.y * gx + blockIdx.x;
  const int gs  = (g & 7) * (nwg >> 3) + (g >> 3);
  const long tM = (long)(gs / gx) * 128;
  const int  tN = (gs % gx) * 128;
  const int sgrow = lane >> 3;                       // row within 8-row group
  const int scol  = ((lane & 7) ^ sgrow) * 8;        // pre-swizzled global col
  const int wm = (wid >> 1) * 64;
  const int wn = (wid & 1) * 64;

  f32x4 acc[4][4];
  #pragma unroll
  for (int i = 0; i < 4; ++i)
    #pragma unroll
    for (int j = 0; j < 4; ++j) acc[i][j] = (f32x4){0.f, 0.f, 0.f, 0.f};

  const int nt = K / 64;
  f16x8 af[2][4], bf[2][4];

  auto stage_tile = [&](int tt) {
    const int k0 = tt * 64;
    f16* Ad = &As[tt & 1][0];
    f16* Bd = &Bs[tt & 1][0];
    #pragma unroll
    for (int u = 0; u < 4; ++u) {
      const int gidx = wid * 4 + u;                  // group 0..15
      const int row  = gidx * 8 + sgrow;             // 0..127
      __builtin_amdgcn_global_load_lds(AS1(A + (tM + row) * K + k0 + scol),
                                       AS3(&Ad[gidx * 512]), 16, 0, 0);
      __builtin_amdgcn_global_load_lds(AS1(Bw + (long)(tN + row) * K + k0 + scol),
                                       AS3(&Bd[gidx * 512]), 16, 0, 0);
    }
  };
  auto load_frags = [&](int cb) {
    #pragma unroll
    for (int kk = 0; kk < 2; ++kk) {
      #pragma unroll
      for (int i = 0; i < 4; ++i) {
        const int row = wm + i * 16 + l16;
        af[kk][i] = *(const f16x8*)&As[cb][row * 64 + (((kk << 2) | qd) ^ (row & 7)) * 8];
      }
      #pragma unroll
      for (int j = 0; j < 4; ++j) {
        const int row = wn + j * 16 + l16;
        bf[kk][j] = *(const f16x8*)&Bs[cb][row * 64 + (((kk << 2) | qd) ^ (row & 7)) * 8];
      }
    }
  };
  auto do_mfma = [&]() {
    #pragma unroll
    for (int kk = 0; kk < 2; ++kk)
      #pragma unroll
      for (int i = 0; i < 4; ++i)
        #pragma unroll
        for (int j = 0; j < 4; ++j)
          acc[i][j] = __builtin_amdgcn_mfma_f32_16x16x32_f16(af[kk][i], bf[kk][j], acc[i][j], 0, 0, 0);
  };

  stage_tile(0);
  stage_tile(1);

  for (int t = 0; t < nt - 2; ++t) {
    asm volatile("s_waitcnt vmcnt(8)" ::: "memory");
    __builtin_amdgcn_s_barrier();
    load_frags(t & 1);
    asm volatile("s_waitcnt lgkmcnt(0)" ::: "memory");
    __builtin_amdgcn_s_barrier();
    stage_tile(t + 2);
    do_mfma();
  }
  asm volatile("s_waitcnt vmcnt(8)" ::: "memory");
  __builtin_amdgcn_s_barrier();
  load_frags(nt & 1);
  do_mfma();
  asm volatile("s_waitcnt vmcnt(0)" ::: "memory");
  __builtin_amdgcn_s_barrier();
  load_frags((nt - 1) & 1);   // buf 1; epilogue slices live in As[0] -> no alias
  do_mfma();

  float bb[4];
  #pragma unroll
  for (int j = 0; j < 4; ++j) bb[j] = bias[tN + wn + j * 16 + l16];

  // Wave-private LDS-staged f16 epilogue, barrier-free.
  f16* slice = &As[0][0] + wid * 1024;  // per-wave 16x64 tile (2 KB)
  const int rrow = lane >> 3;          // 0..7
  const int seg  = lane & 7;           // 0..7
  #pragma unroll
  for (int i = 0; i < 4; ++i) {
    #pragma unroll
    for (int j = 0; j < 4; ++j) {
      #pragma unroll
      for (int r = 0; r < 4; ++r) {
        float v = acc[i][j][r] + bb[j];
        const int r16 = qd * 4 + r;
        slice[r16 * 64 + ((j * 16 + l16) ^ ((r16 & 7) << 3))] = (f16)v;
      }
    }
    #pragma unroll
    for (int hrow = 0; hrow < 16; hrow += 8) {
      const int lrow = hrow + rrow;                       // 0..15
      const f16x8 v8 = *(const f16x8*)(slice + lrow * 64 + (seg ^ (lrow & 7)) * 8);
      const long grow = tM + wm + i * 16 + lrow;
      const int  gc   = tN + wn + seg * 8;
      if (EPI == 1) {
        const int rw = (int)grow;
        const int wi = rw >> 6, n = rw & 63;
        const int bI = wi >> 6, wloc = wi & 63;
        const int hh = (wloc >> 3) * 8 + (n >> 3);
        const int w2 = (wloc & 7) * 8 + (n & 7);
        const long prow = (long)bI * 4096 + hh * 64 + w2;
        const float* rp = residf + prow * 256 + gc;
        f16x8 o;
        #pragma unroll
        for (int k = 0; k < 8; ++k) o[k] = (f16)(rp[k] + (float)v8[k]);
        *(f16x8*)(outh + prow * 256 + gc) = o;
      } else {
        *(f16x8*)(outh + grow * N + gc) = v8;
      }
    }
  }
}

// ---------------- fused FFN (64-row tiles): out = x1 + gelu(xn2@w1^T+b1)@w2^T + b2
// 512 threads = 8 waves; ALL waves cover the same 64 rows, each owns 32 cols.
// Register state per wave: acch[4][2] + acc2[4][2] = 64 VGPR accumulators
// (half of round-8's 128, which spilled). __launch_bounds__(512,4) caps VGPR
// at 128 -> no spill; LDS 65KB -> 2 blocks/CU for cross-block phase overlap.
// As [64][256] swizzled (gload_lds both-sides involution, 2-way max).
// Hs [64][264] PADDED (+16B/row): plain indexing, banks uniform.
__global__ __launch_bounds__(512, 4) void ffn_fused(
    const f16* __restrict__ A, const f16* __restrict__ W1p, const f16* __restrict__ W2p,
    const float* __restrict__ b1f, const float* __restrict__ b2f,
    const f16* __restrict__ residh, float* __restrict__ outf) {
  __shared__ f16 As[64 * 256];
  __shared__ f16 Hs[64 * 264];
  const int tid = threadIdx.x;
  const int wid = tid >> 6, lane = tid & 63;
  const int qd = lane >> 4, l16 = lane & 15;
  const int wn = wid * 32;                 // wave's 32-col slice
  const int nwg = gridDim.x;
  const int g = blockIdx.x;
  const int gs = (g & 7) * (nwg >> 3) + (g >> 3);
  const long tM = (long)gs * 64;

  // ---- stage A once: 64 rows x 512B, 4 rounds x 8KB ----
  #pragma unroll
  for (int u = 0; u < 4; ++u) {
    const int row = u * 16 + (tid >> 5);
    const int c = tid & 31;
    const int cs = (c & ~7) | ((c & 7) ^ (row & 7));   // involution pre-swizzle
    __builtin_amdgcn_global_load_lds(AS1(A + (tM + row) * 256 + cs * 8),
                                     AS3(&As[row * 256 + c * 8]), 16, 0, 0);
  }
  asm volatile("s_waitcnt vmcnt(0)" ::: "memory");
  __builtin_amdgcn_s_barrier();

  f32x4 acc2[4][2];
  #pragma unroll
  for (int i = 0; i < 4; ++i) {
    acc2[i][0] = (f32x4){0.f, 0.f, 0.f, 0.f};
    acc2[i][1] = (f32x4){0.f, 0.f, 0.f, 0.f};
  }

  for (int hc = 0; hc < 4; ++hc) {
    // ---- fc1 chunk: acch = A @ w1[hc*256 + wn .. +32, :]^T  (K=256) ----
    f32x4 acch[4][2];
    #pragma unroll
    for (int i = 0; i < 4; ++i) {
      acch[i][0] = (f32x4){0.f, 0.f, 0.f, 0.f};
      acch[i][1] = (f32x4){0.f, 0.f, 0.f, 0.f};
    }
    #pragma unroll 2
    for (int kk = 0; kk < 8; ++kk) {
      f16x8 a4[4], b4[2];
      #pragma unroll
      for (int i = 0; i < 4; ++i) {
        const int row = i * 16 + l16;
        const int cg = kk * 4 + qd;
        const int cs = (cg & ~7) | ((cg & 7) ^ (row & 7));
        a4[i] = *(const f16x8*)&As[row * 256 + cs * 8];
      }
      #pragma unroll
      for (int j = 0; j < 2; ++j) {
        const int n16 = hc * 16 + wid * 2 + j;
        b4[j] = *(const f16x8*)(W1p + ((long)((n16 * 8 + kk) * 64 + lane) << 3));
      }
      #pragma unroll
      for (int i = 0; i < 4; ++i) {
        acch[i][0] = __builtin_amdgcn_mfma_f32_16x16x32_f16(a4[i], b4[0], acch[i][0], 0, 0, 0);
        acch[i][1] = __builtin_amdgcn_mfma_f32_16x16x32_f16(a4[i], b4[1], acch[i][1], 0, 0, 0);
      }
    }
    __syncthreads();   // previous hc's fc2 reads of Hs complete
    // ---- gelu + bias -> Hs (padded rows, plain indexing) ----
    #pragma unroll
    for (int j = 0; j < 2; ++j) {
      const float bb1 = b1f[hc * 256 + wn + j * 16 + l16];
      #pragma unroll
      for (int i = 0; i < 4; ++i) {
        #pragma unroll
        for (int r = 0; r < 4; ++r) {
          float v = acch[i][j][r] + bb1;
          const float u2 = v * v;
          const float w  = v * (-2.3022082f - 0.10294324f * u2);
          const float e  = __builtin_amdgcn_exp2f(w);
          v = v * __builtin_amdgcn_rcpf(1.0f + e);
          const int row = i * 16 + qd * 4 + r;
          Hs[row * 264 + wn + j * 16 + l16] = (f16)v;
        }
      }
    }
    __syncthreads();   // Hs visible to all waves
    // ---- fc2 chunk: acc2 += Hs @ w2[wn .. +32, hc*256 ..]^T ----
    #pragma unroll 2
    for (int kk = 0; kk < 8; ++kk) {
      f16x8 ah[4], bh[2];
      #pragma unroll
      for (int i = 0; i < 4; ++i) {
        const int row = i * 16 + l16;
        ah[i] = *(const f16x8*)&Hs[row * 264 + kk * 32 + qd * 8];
      }
      #pragma unroll
      for (int j = 0; j < 2; ++j) {
        const int n16 = wid * 2 + j;
        bh[j] = *(const f16x8*)(W2p + ((long)((n16 * 32 + hc * 8 + kk) * 64 + lane) << 3));
      }
      #pragma unroll
      for (int i = 0; i < 4; ++i) {
        acc2[i][0] = __builtin_amdgcn_mfma_f32_16x16x32_f16(ah[i], bh[0], acc2[i][0], 0, 0, 0);
        acc2[i][1] = __builtin_amdgcn_mfma_f32_16x16x32_f16(ah[i], bh[1], acc2[i][1], 0, 0, 0);
      }
    }
  }

  // ---- epilogue: out fp32 = x1h + acc2 + b2 (64B-sector stores) ----
  #pragma unroll
  for (int j = 0; j < 2; ++j) {
    const int col = wn + j * 16 + l16;
    const float bb2 = b2f[col];
    #pragma unroll
    for (int i = 0; i < 4; ++i) {
      #pragma unroll
      for (int r = 0; r < 4; ++r) {
        const long row = tM + i * 16 + qd * 4 + r;
        const long off = row * 256 + col;
        outf[off] = (float)residh[off] + acc2[i][j][r] + bb2;
      }
    }
  }
}

// ---------------- windowed attention: MFMA flash, one wave per (window, head) ----------------
__global__ __launch_bounds__(256, 3) void attn_win(
    const f16* __restrict__ qkv, const float* __restrict__ bt,  // bt = T[8][64][64] pre-scaled
    f16* __restrict__ out) {
  __shared__ __align__(16) char SMEM[4 * 12800];
  const int wid = threadIdx.x >> 6, lane = threadIdx.x & 63;
  const int qd = lane >> 4, l16 = lane & 15;
  const int unit = blockIdx.x * 4 + wid;   // (window,head) unit within chunk
  const int wi = unit >> 3, h = unit & 7;
  char* W = SMEM + wid * 12800;
  f16* VT = (f16*)W;               // stride 72 f16 per d-row
  char* Pb = W + 4608;

  const f16* qbase = qkv + (long)wi * 64 * 768 + h * 32;

  f16x8 qa[4], kb[4];
  #pragma unroll
  for (int i = 0; i < 4; ++i)
    qa[i] = *(const f16x8*)(qbase + (16 * i + l16) * 768 + qd * 8);
  #pragma unroll
  for (int j = 0; j < 4; ++j)
    kb[j] = *(const f16x8*)(qbase + 256 + (16 * j + l16) * 768 + qd * 8);

  #pragma unroll
  for (int it = 0; it < 4; ++it) {
    const f16x8 v8 = *(const f16x8*)(qbase + 512 + (16 * it + l16) * 768 + qd * 8);
    #pragma unroll
    for (int e = 0; e < 8; ++e)
      VT[(qd * 8 + e) * 72 + 16 * it + l16] = v8[e];
  }

  f32x4 S[4][4];
  #pragma unroll
  for (int i = 0; i < 4; ++i)
    #pragma unroll
    for (int j = 0; j < 4; ++j) S[i][j] = (f32x4){0.f, 0.f, 0.f, 0.f};
  #pragma unroll
  for (int i = 0; i < 4; ++i)
    #pragma unroll
    for (int j = 0; j < 4; ++j)
      S[i][j] = __builtin_amdgcn_mfma_f32_16x16x32_f16(qa[i], kb[j], S[i][j], 0, 0, 0);

  const float SC = 0.17677669529663687f * 1.4426950408889634f;  // 1/sqrt(32)*log2e
  const float* Tb = bt + ((h * 64 + lane) << 6);
  #pragma unroll
  for (int i = 0; i < 4; ++i) {
    f32x4 b0 = *(const f32x4*)(Tb + i * 16);
    f32x4 b1 = *(const f32x4*)(Tb + i * 16 + 4);
    f32x4 b2 = *(const f32x4*)(Tb + i * 16 + 8);
    f32x4 b3 = *(const f32x4*)(Tb + i * 16 + 12);
    #pragma unroll
    for (int r = 0; r < 4; ++r) {
      S[i][0][r] = S[i][0][r] * SC + b0[r];
      S[i][1][r] = S[i][1][r] * SC + b1[r];
      S[i][2][r] = S[i][2][r] * SC + b2[r];
      S[i][3][r] = S[i][3][r] * SC + b3[r];
    }
  }

  float inv[4][4];
  #pragma unroll
  for (int i = 0; i < 4; ++i) {
    #pragma unroll
    for (int r = 0; r < 4; ++r) {
      float mx = fmaxf(fmaxf(S[i][0][r], S[i][1][r]), fmaxf(S[i][2][r], S[i][3][r]));
      #pragma unroll
      for (int msk = 1; msk < 16; msk <<= 1) mx = fmaxf(mx, __shfl_xor(mx, msk));
      float s0 = 0.f;
      #pragma unroll
      for (int j = 0; j < 4; ++j) {
        const float p = __builtin_amdgcn_exp2f(S[i][j][r] - mx);
        S[i][j][r] = p;
        s0 += p;
      }
      #pragma unroll
      for (int msk = 1; msk < 16; msk <<= 1) s0 += __shfl_xor(s0, msk);
      inv[i][r] = __builtin_amdgcn_rcpf(s0);
    }
  }

  #pragma unroll
  for (int i = 0; i < 4; ++i) {
    #pragma unroll
    for (int r = 0; r < 4; ++r) {
      const int n = 16 * i + 4 * qd + r;
      char* rowp = Pb + n * 128;
      const int sw = (n & 7) << 4;
      #pragma unroll
      for (int j = 0; j < 4; ++j)
        *(f16*)(rowp + ((j * 32 + l16 * 2) ^ sw)) = (f16)S[i][j][r];
    }
  }

  f32x4 O[4][2];
  #pragma unroll
  for (int i = 0; i < 4; ++i) {
    O[i][0] = (f32x4){0.f, 0.f, 0.f, 0.f};
    O[i][1] = (f32x4){0.f, 0.f, 0.f, 0.f};
  }
  #pragma unroll
  for (int kk = 0; kk < 2; ++kk) {
    f16x8 vb[2];
    #pragma unroll
    for (int jj = 0; jj < 2; ++jj)
      vb[jj] = *(const f16x8*)((const char*)W + (16 * jj + l16) * 144 + kk * 64 + qd * 16);
    #pragma unroll
    for (int i = 0; i < 4; ++i) {
      const f16x8 pa = *(const f16x8*)(Pb + (16 * i + l16) * 128 +
                                       ((kk * 64 + qd * 16) ^ ((l16 & 7) << 4)));
      #pragma unroll
      for (int jj = 0; jj < 2; ++jj)
        O[i][jj] = __builtin_amdgcn_mfma_f32_16x16x32_f16(pa, vb[jj], O[i][jj], 0, 0, 0);
    }
  }

  #pragma unroll
  for (int i = 0; i < 4; ++i) {
    #pragma unroll
    for (int jj = 0; jj < 2; ++jj) {
      #pragma unroll
      for (int r = 0; r < 4; ++r) {
        const int n = 16 * i + 4 * qd + r;
        *(f16*)(Pb + n * 80 + jj * 32 + l16 * 2) = (f16)(O[i][jj][r] * inv[i][r]);
      }
    }
  }
  #pragma unroll
  for (int it = 0; it < 4; ++it) {
    const int row = 16 * it + l16;
    const f16x8 o8 = *(const f16x8*)(Pb + row * 80 + qd * 16);
    *(f16x8*)(out + ((long)wi * 64 + row) * 256 + h * 32 + qd * 8) = o8;
  }
}

// ---------------- launch ----------------
extern "C" void kernel_launch(void* const* d_in, const int* in_sizes, int n_in,
                              void* d_out, int out_size, void* d_ws, size_t ws_size,
                              hipStream_t stream) {
  const float* x     = (const float*)d_in[0];
  const float* g1    = (const float*)d_in[2];
  const float* b1    = (const float*)d_in[3];
  const float* wqkv  = (const float*)d_in[4];
  const float* bqkv  = (const float*)d_in[5];
  const float* btab  = (const float*)d_in[6];
  const float* wproj = (const float*)d_in[7];
  const float* bproj = (const float*)d_in[8];
  const float* g2    = (const float*)d_in[9];
  const float* b2    = (const float*)d_in[10];
  const float* wfc1  = (const float*)d_in[11];
  const float* bfc1  = (const float*)d_in[12];
  const float* wfc2  = (const float*)d_in[13];
  const float* bfc2  = (const float*)d_in[14];
  float* out = (float*)d_out;

  char* ws = (char*)d_ws;
  // head region [0, 2MB): wq16+wp16 512KB | Tbuf 128KB | W1p 512KB | W2p 512KB
  f16* wq16 = (f16*)ws;                       // 196608 f16
  f16* wp16 = wq16 + 196608;                  // 65536 f16, ends at 512KB
  float* Tbuf = (float*)(ws + 524288);        // 128KB
  f16* W1p = (f16*)(ws + 655360);             // 512KB
  f16* W2p = (f16*)(ws + 1179648);            // 512KB, ends at ~1.66MB

  // Per-image f16 buffers: xn 2MB | qkv 6MB | x1 2MB | xn2 2MB
  int CH = 1;
  for (int cand = 32; cand >= 1; cand >>= 1) {
    const size_t need = 2097152ULL + (size_t)cand * 12582912ULL;
    if (need <= ws_size) { CH = cand; break; }
  }
  const int NC = 32 / CH;

  const size_t O_xn  = 2097152ULL;
  const size_t O_qkv = O_xn  + (size_t)CH * 2097152ULL;
  const size_t O_x1  = O_qkv + (size_t)CH * 6291456ULL;
  const size_t O_xn2 = O_x1  + (size_t)CH * 2097152ULL;
  f16* xnw  = (f16*)(ws + O_xn);    // ln1 out / attn out
  f16* qkvb = (f16*)(ws + O_qkv);
  f16* x1h  = (f16*)(ws + O_x1);
  f16* xn2  = (f16*)(ws + O_xn2);

  cvt_weights<<<1024, 256, 0, stream>>>(wqkv, wproj, wq16);
  prep_bias<<<128, 256, 0, stream>>>(btab, Tbuf);
  prep_wfrag<<<256, 256, 0, stream>>>(wfc1, wfc2, W1p, W2p);

  const long imgElems = 4096L * 256;   // fp32 elems per image
  for (int c = 0; c < NC; ++c) {
    const float* xc  = x   + (long)c * CH * imgElems;
    float*       oc  = out + (long)c * CH * imgElems;
    ln_rows<true, float><<<CH * 1024, 256, 0, stream>>>(xc, g1, b1, xnw);
    gemm_bt<0, 256><<<dim3(6, CH * 32), 256, 0, stream>>>(xnw, wq16, bqkv, nullptr, nullptr, qkvb, nullptr, 768);
    attn_win<<<CH * 128, 256, 0, stream>>>(qkvb, Tbuf, xnw);
    gemm_bt<1, 256><<<dim3(2, CH * 32), 256, 0, stream>>>(xnw, wp16, bproj, xc, nullptr, x1h, nullptr, 256);
    ln_rows<false, f16><<<CH * 1024, 256, 0, stream>>>(x1h, g2, b2, xn2);
    ffn_fused<<<CH * 64, 512, 0, stream>>>(xn2, W1p, W2p, bfc1, bfc2, x1h, oc);
  }
}